// Round 1
// baseline (2505.973 us; speedup 1.0000x reference)
//
#include <hip/hip_runtime.h>
#include <math.h>

#define DIMC  512
#define HEADS 8
#define HD    64
#define NPIX  16384   // 128*128
#define LTOK  256     // 16*16
#define BATCH 2
#define WIMG  128
#define KVK   32768   // 512*8*8
#define EPSB  1e-8f
#define SCALEF 0.125f // 64^-0.5

// ---------------- mask downsample (avg pool 8x8) ----------------
__global__ void k_maskdown(const float* __restrict__ mask, float* __restrict__ md) {
    int b = blockIdx.x;
    int l = threadIdx.x;            // 256 threads = 256 l
    int hr = l >> 4, wr = l & 15;
    const float* mp = mask + (size_t)b * NPIX;
    float s = 0.f;
#pragma unroll
    for (int i = 0; i < 8; ++i)
#pragma unroll
        for (int j = 0; j < 8; ++j)
            s += mp[(hr * 8 + i) * WIMG + wr * 8 + j];
    md[b * LTOK + l] = s * (1.f / 64.f);
}

// ---------------- 1x1 conv as GEMM: Y[b,o,n] = sum_c W[o,c] X[b,c,n] ----------------
// grid: (N/64, 512/64, B); block 256; tile 64x64, BK=16, micro 4x4
__global__ __launch_bounds__(256) void k_conv1x1(const float* __restrict__ X,
                                                 const float* __restrict__ W,
                                                 float* __restrict__ Y) {
    __shared__ float As[16][68];  // [kk][m]
    __shared__ float Bs[16][68];  // [kk][n]
    const int b  = blockIdx.z;
    const int m0 = blockIdx.y * 64, n0 = blockIdx.x * 64;
    const int tid = threadIdx.x;
    const int mg = tid >> 4, ng = tid & 15;
    const int lka = tid & 15, lma = tid >> 4;   // A loader: lane->k
    const int lnb = tid & 63, lkb = tid >> 6;   // B loader: lane->n
    float acc[4][4] = {{0.f}};
    const float* Xb = X + (size_t)b * DIMC * NPIX;

    for (int k0 = 0; k0 < DIMC; k0 += 16) {
#pragma unroll
        for (int p = 0; p < 4; ++p)
            As[lka][lma + p * 16] = W[(size_t)(m0 + lma + p * 16) * DIMC + k0 + lka];
#pragma unroll
        for (int p = 0; p < 4; ++p)
            Bs[lkb + p * 4][lnb] = Xb[(size_t)(k0 + lkb + p * 4) * NPIX + n0 + lnb];
        __syncthreads();
#pragma unroll
        for (int kk = 0; kk < 16; ++kk) {
            float a[4], bv[4];
            *(float4*)a  = *(const float4*)&As[kk][mg * 4];
            *(float4*)bv = *(const float4*)&Bs[kk][ng * 4];
#pragma unroll
            for (int i = 0; i < 4; ++i)
#pragma unroll
                for (int j = 0; j < 4; ++j)
                    acc[i][j] += a[i] * bv[j];
        }
        __syncthreads();
    }
    float* Yb = Y + (size_t)b * DIMC * NPIX;
#pragma unroll
    for (int i = 0; i < 4; ++i) {
        float4 v = make_float4(acc[i][0], acc[i][1], acc[i][2], acc[i][3]);
        *(float4*)&Yb[(size_t)(m0 + mg * 4 + i) * NPIX + n0 + ng * 4] = v;
    }
}

// ---------------- kv conv (8x8 stride 8) as im2col GEMM, split-K=2 ----------------
// part[ks][b][o][l] = sum_{k in chunk} Wkv[o,k] xcol[b,k,l]
// grid: (256/64, 1024/64, B*2); block 256
__global__ __launch_bounds__(256) void k_convkv(const float* __restrict__ X,
                                                const float* __restrict__ Wkv,
                                                float* __restrict__ part) {
    __shared__ float As[16][68];
    __shared__ float Bs[16][68];
    const int bz = blockIdx.z;
    const int b = bz >> 1, ks = bz & 1;
    const int m0 = blockIdx.y * 64, n0 = blockIdx.x * 64;
    const int tid = threadIdx.x;
    const int mg = tid >> 4, ng = tid & 15;
    const int lka = tid & 15, lma = tid >> 4;
    const int lnb = tid & 63, lkb = tid >> 6;
    float acc[4][4] = {{0.f}};
    const float* Xb = X + (size_t)b * DIMC * NPIX;
    const int l = n0 + lnb, hr = l >> 4, wr = l & 15;
    const int rowbase = (hr * 8) * WIMG + wr * 8;
    const int kbeg = ks * 16384, kend = kbeg + 16384;

    for (int k0 = kbeg; k0 < kend; k0 += 16) {
#pragma unroll
        for (int p = 0; p < 4; ++p)
            As[lka][lma + p * 16] = Wkv[(size_t)(m0 + lma + p * 16) * KVK + k0 + lka];
#pragma unroll
        for (int p = 0; p < 4; ++p) {
            int kg = k0 + lkb + p * 4;
            int c = kg >> 6, ij = kg & 63, ii = ij >> 3, jj = ij & 7;
            Bs[lkb + p * 4][lnb] = Xb[(size_t)c * NPIX + rowbase + ii * WIMG + jj];
        }
        __syncthreads();
#pragma unroll
        for (int kk = 0; kk < 16; ++kk) {
            float a[4], bv[4];
            *(float4*)a  = *(const float4*)&As[kk][mg * 4];
            *(float4*)bv = *(const float4*)&Bs[kk][ng * 4];
#pragma unroll
            for (int i = 0; i < 4; ++i)
#pragma unroll
                for (int j = 0; j < 4; ++j)
                    acc[i][j] += a[i] * bv[j];
        }
        __syncthreads();
    }
    float* P = part + ((size_t)ks * BATCH + b) * (1024 * 256);
#pragma unroll
    for (int i = 0; i < 4; ++i) {
        float4 v = make_float4(acc[i][0], acc[i][1], acc[i][2], acc[i][3]);
        *(float4*)&P[(size_t)(m0 + mg * 4 + i) * 256 + n0 + ng * 4] = v;
    }
}

__global__ void k_kvreduce(const float* __restrict__ part, float* __restrict__ kv) {
    int idx = blockIdx.x * 256 + threadIdx.x;   // 2*1024*256 = 524288 total
    kv[idx] = part[idx] + part[idx + BATCH * 1024 * 256];
}

// ---------------- fused attention ----------------
// per block: one (b,h), 64 q-rows. sim GEMM -> +log-bias*scale -> softmax -> PV
// NOTE the reference's torch-repeat quirk: bias batch index = (b*HEADS+h) % B
__global__ __launch_bounds__(256) void k_attn(const float* __restrict__ qbuf,
                                              const float* __restrict__ kvbuf,
                                              const float* __restrict__ mask,
                                              const float* __restrict__ md,
                                              float* __restrict__ obuf) {
    __shared__ float KVs[256][68];   // K then (reused) V, [l][d]
    __shared__ float Qs[64][68];     // [n][d]
    __shared__ float Ss[256][68];    // [l][n]
    __shared__ float invs[64];

    const int n0 = blockIdx.x * 64;
    const int bh = blockIdx.y;          // = b*HEADS + h
    const int b = bh >> 3, h = bh & 7;
    const int bb = bh % BATCH;          // bias batch quirk
    const int tid = threadIdx.x;

    // stage Q: Qs[n][d]
    {
        const int nn = tid & 63, db = tid >> 6;
        const float* qp = qbuf + (size_t)(b * DIMC + h * HD) * NPIX + n0 + nn;
#pragma unroll
        for (int p = 0; p < 16; ++p) {
            int d = db + p * 4;
            Qs[nn][d] = qp[(size_t)d * NPIX];
        }
    }
    // stage K: KVs[l][d]
    {
        const float* kp = kvbuf + (size_t)(b * 1024 + h * HD) * LTOK + tid;
#pragma unroll
        for (int d = 0; d < HD; ++d)
            KVs[tid][d] = kp[(size_t)d * LTOK];
    }
    __syncthreads();

    // sim GEMM: thread (lg,ng): n = ng*4+i, l = lg + 16*j (interleaved to avoid bank conflicts)
    const int lg = tid >> 4, ng = tid & 15;
    float acc[4][16];
#pragma unroll
    for (int i = 0; i < 4; ++i)
#pragma unroll
        for (int j = 0; j < 16; ++j) acc[i][j] = 0.f;

#pragma unroll 2
    for (int kk = 0; kk < HD; kk += 4) {
        float qv[4][4];
#pragma unroll
        for (int i = 0; i < 4; ++i)
            *(float4*)qv[i] = *(const float4*)&Qs[ng * 4 + i][kk];
#pragma unroll
        for (int j = 0; j < 16; ++j) {
            float kv4[4];
            *(float4*)kv4 = *(const float4*)&KVs[lg + 16 * j][kk];
#pragma unroll
            for (int i = 0; i < 4; ++i)
                acc[i][j] += qv[i][0] * kv4[0] + qv[i][1] * kv4[1] +
                             qv[i][2] * kv4[2] + qv[i][3] * kv4[3];
        }
    }
    // epilogue: sim = (qk + log(m*md + eps)) * scale  -> Ss[l][n]
    {
        float mreg[4];
#pragma unroll
        for (int i = 0; i < 4; ++i)
            mreg[i] = mask[(size_t)bb * NPIX + n0 + ng * 4 + i];
#pragma unroll
        for (int j = 0; j < 16; ++j) {
            int l = lg + 16 * j;
            float mdv = md[bb * LTOK + l];
            float v[4];
#pragma unroll
            for (int i = 0; i < 4; ++i)
                v[i] = (acc[i][j] + logf(mreg[i] * mdv + EPSB)) * SCALEF;
            *(float4*)&Ss[l][ng * 4] = *(float4*)v;
        }
    }
    __syncthreads();

    // stage V (overwrite KVs) + softmax over l per n (4 lanes per row)
    {
        const float* vp = kvbuf + (size_t)(b * 1024 + 512 + h * HD) * LTOK + tid;
#pragma unroll
        for (int d = 0; d < HD; ++d)
            KVs[tid][d] = vp[(size_t)d * LTOK];
    }
    {
        const int n = tid >> 2, t = tid & 3;
        float s[64];
#pragma unroll
        for (int ii = 0; ii < 64; ++ii) s[ii] = Ss[t + 4 * ii][n];
        float mx = s[0];
#pragma unroll
        for (int ii = 1; ii < 64; ++ii) mx = fmaxf(mx, s[ii]);
        mx = fmaxf(mx, __shfl_xor(mx, 1));
        mx = fmaxf(mx, __shfl_xor(mx, 2));
        float sum = 0.f;
#pragma unroll
        for (int ii = 0; ii < 64; ++ii) {
            s[ii] = expf(s[ii] - mx);
            sum += s[ii];
        }
        sum += __shfl_xor(sum, 1);
        sum += __shfl_xor(sum, 2);
#pragma unroll
        for (int ii = 0; ii < 64; ++ii) Ss[t + 4 * ii][n] = s[ii];
        if (t == 0) invs[n] = 1.f / sum;
    }
    __syncthreads();

    // PV: out[n,d] = inv[n] * sum_l e[l,n] * V[l,d];  thread (dg,ng): d=dg*4+j, n=ng*4+i
    {
        const int dg = tid >> 4;
        float acc2[4][4] = {{0.f}};
#pragma unroll 8
        for (int kk = 0; kk < LTOK; ++kk) {
            float sv[4], vv[4];
            *(float4*)sv = *(const float4*)&Ss[kk][ng * 4];
            *(float4*)vv = *(const float4*)&KVs[kk][dg * 4];
#pragma unroll
            for (int i = 0; i < 4; ++i)
#pragma unroll
                for (int j = 0; j < 4; ++j)
                    acc2[i][j] += sv[i] * vv[j];
        }
        float iv[4];
#pragma unroll
        for (int i = 0; i < 4; ++i) iv[i] = invs[ng * 4 + i];
        float* op = obuf + (size_t)(b * DIMC + h * HD) * NPIX;
#pragma unroll
        for (int j = 0; j < 4; ++j) {
            int d = dg * 4 + j;
            float4 ov = make_float4(acc2[0][j] * iv[0], acc2[1][j] * iv[1],
                                    acc2[2][j] * iv[2], acc2[3][j] * iv[3]);
            *(float4*)&op[(size_t)d * NPIX + n0 + ng * 4] = ov;
        }
    }
}

extern "C" void kernel_launch(void* const* d_in, const int* in_sizes, int n_in,
                              void* d_out, int out_size, void* d_ws, size_t ws_size,
                              hipStream_t stream) {
    const float* x    = (const float*)d_in[0];
    const float* mask = (const float*)d_in[1];
    const float* Wq   = (const float*)d_in[2];
    const float* Wkv  = (const float*)d_in[3];
    const float* Wo   = (const float*)d_in[4];
    float* out = (float*)d_out;

    char* ws = (char*)d_ws;
    float* md   = (float*)(ws);                                    // 512 f
    float* q    = (float*)(ws + 4096);                             // 2*512*16384 f = 64MB
    float* ao   = (float*)(ws + 4096 + 67108864);                  // 64MB
    float* kv   = (float*)(ws + 4096 + 2 * 67108864);              // 2MB
    float* part = (float*)(ws + 4096 + 2 * 67108864 + 2097152);    // 4MB

    k_maskdown<<<dim3(BATCH), dim3(256), 0, stream>>>(mask, md);
    k_conv1x1<<<dim3(NPIX / 64, DIMC / 64, BATCH), dim3(256), 0, stream>>>(x, Wq, q);
    k_convkv<<<dim3(LTOK / 64, 1024 / 64, BATCH * 2), dim3(256), 0, stream>>>(x, Wkv, part);
    k_kvreduce<<<dim3(2048), dim3(256), 0, stream>>>(part, kv);
    k_attn<<<dim3(NPIX / 64, BATCH * HEADS), dim3(256), 0, stream>>>(q, kv, mask, md, ao);
    k_conv1x1<<<dim3(NPIX / 64, DIMC / 64, BATCH), dim3(256), 0, stream>>>(ao, Wo, out);
}

// Round 2
// 1634.291 us; speedup vs baseline: 1.5334x; 1.5334x over previous
//
#include <hip/hip_runtime.h>
#include <math.h>

#define DIMC  512
#define HEADS 8
#define HD    64
#define NPIX  16384   // 128*128
#define LTOK  256     // 16*16
#define BATCH 2
#define WIMG  128
#define KVK   32768   // 512*8*8
#define EPSB  1e-8f
#define SCALEF 0.125f // 64^-0.5
#define SPLITK 16
#define KCHUNK (KVK / SPLITK)   // 2048

// ---------------- mask downsample (avg pool 8x8) ----------------
__global__ void k_maskdown(const float* __restrict__ mask, float* __restrict__ md) {
    int b = blockIdx.x;
    int l = threadIdx.x;            // 256 threads = 256 l
    int hr = l >> 4, wr = l & 15;
    const float* mp = mask + (size_t)b * NPIX;
    float s = 0.f;
#pragma unroll
    for (int i = 0; i < 8; ++i)
#pragma unroll
        for (int j = 0; j < 8; ++j)
            s += mp[(hr * 8 + i) * WIMG + wr * 8 + j];
    md[b * LTOK + l] = s * (1.f / 64.f);
}

// ---------------- 1x1 conv as GEMM: Y[b,o,n] = sum_c W[o,c] X[b,c,n] ----------------
// grid: (N/64, 512/64, B); block 256; tile 64x64, BK=16, micro 4x4
__global__ __launch_bounds__(256) void k_conv1x1(const float* __restrict__ X,
                                                 const float* __restrict__ W,
                                                 float* __restrict__ Y) {
    __shared__ float As[16][68];  // [kk][m]
    __shared__ float Bs[16][68];  // [kk][n]
    const int b  = blockIdx.z;
    const int m0 = blockIdx.y * 64, n0 = blockIdx.x * 64;
    const int tid = threadIdx.x;
    const int mg = tid >> 4, ng = tid & 15;
    const int lka = tid & 15, lma = tid >> 4;   // A loader: lane->k
    const int lnb = tid & 63, lkb = tid >> 6;   // B loader: lane->n
    float acc[4][4] = {{0.f}};
    const float* Xb = X + (size_t)b * DIMC * NPIX;

    for (int k0 = 0; k0 < DIMC; k0 += 16) {
#pragma unroll
        for (int p = 0; p < 4; ++p)
            As[lka][lma + p * 16] = W[(size_t)(m0 + lma + p * 16) * DIMC + k0 + lka];
#pragma unroll
        for (int p = 0; p < 4; ++p)
            Bs[lkb + p * 4][lnb] = Xb[(size_t)(k0 + lkb + p * 4) * NPIX + n0 + lnb];
        __syncthreads();
#pragma unroll
        for (int kk = 0; kk < 16; ++kk) {
            float a[4], bv[4];
            *(float4*)a  = *(const float4*)&As[kk][mg * 4];
            *(float4*)bv = *(const float4*)&Bs[kk][ng * 4];
#pragma unroll
            for (int i = 0; i < 4; ++i)
#pragma unroll
                for (int j = 0; j < 4; ++j)
                    acc[i][j] += a[i] * bv[j];
        }
        __syncthreads();
    }
    float* Yb = Y + (size_t)b * DIMC * NPIX;
#pragma unroll
    for (int i = 0; i < 4; ++i) {
        float4 v = make_float4(acc[i][0], acc[i][1], acc[i][2], acc[i][3]);
        *(float4*)&Yb[(size_t)(m0 + mg * 4 + i) * NPIX + n0 + ng * 4] = v;
    }
}

// ---------------- kv conv (8x8 stride 8) as im2col GEMM, split-K=16 ----------------
// part[ks][b][o][l] = sum_{k in chunk ks} Wkv[o,k] xcol[b,k,l]
// grid: (256/64, 1024/64, B*SPLITK); block 256
__global__ __launch_bounds__(256) void k_convkv(const float* __restrict__ X,
                                                const float* __restrict__ Wkv,
                                                float* __restrict__ part) {
    __shared__ float As[16][68];
    __shared__ float Bs[16][68];
    const int bz = blockIdx.z;
    const int b = bz >> 4, ks = bz & (SPLITK - 1);
    const int m0 = blockIdx.y * 64, n0 = blockIdx.x * 64;
    const int tid = threadIdx.x;
    const int mg = tid >> 4, ng = tid & 15;
    const int lka = tid & 15, lma = tid >> 4;
    const int lnb = tid & 63, lkb = tid >> 6;
    float acc[4][4] = {{0.f}};
    const float* Xb = X + (size_t)b * DIMC * NPIX;
    const int l = n0 + lnb, hr = l >> 4, wr = l & 15;
    const int rowbase = (hr * 8) * WIMG + wr * 8;
    const int kbeg = ks * KCHUNK, kend = kbeg + KCHUNK;

    for (int k0 = kbeg; k0 < kend; k0 += 16) {
#pragma unroll
        for (int p = 0; p < 4; ++p)
            As[lka][lma + p * 16] = Wkv[(size_t)(m0 + lma + p * 16) * KVK + k0 + lka];
#pragma unroll
        for (int p = 0; p < 4; ++p) {
            int kg = k0 + lkb + p * 4;
            int c = kg >> 6, ij = kg & 63, ii = ij >> 3, jj = ij & 7;
            Bs[lkb + p * 4][lnb] = Xb[(size_t)c * NPIX + rowbase + ii * WIMG + jj];
        }
        __syncthreads();
#pragma unroll
        for (int kk = 0; kk < 16; ++kk) {
            float a[4], bv[4];
            *(float4*)a  = *(const float4*)&As[kk][mg * 4];
            *(float4*)bv = *(const float4*)&Bs[kk][ng * 4];
#pragma unroll
            for (int i = 0; i < 4; ++i)
#pragma unroll
                for (int j = 0; j < 4; ++j)
                    acc[i][j] += a[i] * bv[j];
        }
        __syncthreads();
    }
    float* P = part + ((size_t)ks * BATCH + b) * (1024 * 256);
#pragma unroll
    for (int i = 0; i < 4; ++i) {
        float4 v = make_float4(acc[i][0], acc[i][1], acc[i][2], acc[i][3]);
        *(float4*)&P[(size_t)(m0 + mg * 4 + i) * 256 + n0 + ng * 4] = v;
    }
}

__global__ void k_kvreduce(const float* __restrict__ part, float* __restrict__ kv) {
    int idx = blockIdx.x * 256 + threadIdx.x;   // 2*1024*256 = 524288 total
    float s = 0.f;
#pragma unroll
    for (int p = 0; p < SPLITK; ++p)
        s += part[idx + (size_t)p * (BATCH * 1024 * 256)];
    kv[idx] = s;
}

// ---------------- fused attention ----------------
// per block: one (b,h), 64 q-rows. sim GEMM -> +log-bias*scale -> softmax -> PV
// NOTE the reference's torch-repeat quirk: bias batch index = (b*HEADS+h) % B
__global__ __launch_bounds__(256) void k_attn(const float* __restrict__ qbuf,
                                              const float* __restrict__ kvbuf,
                                              const float* __restrict__ mask,
                                              const float* __restrict__ md,
                                              float* __restrict__ obuf) {
    __shared__ float KVs[256][68];   // K then (reused) V, [l][d]
    __shared__ float Qs[64][68];     // [n][d]
    __shared__ float Ss[256][68];    // [l][n]
    __shared__ float invs[64];

    const int n0 = blockIdx.x * 64;
    const int bh = blockIdx.y;          // = b*HEADS + h
    const int b = bh >> 3, h = bh & 7;
    const int bb = bh % BATCH;          // bias batch quirk
    const int tid = threadIdx.x;

    // stage Q: Qs[n][d]
    {
        const int nn = tid & 63, db = tid >> 6;
        const float* qp = qbuf + (size_t)(b * DIMC + h * HD) * NPIX + n0 + nn;
#pragma unroll
        for (int p = 0; p < 16; ++p) {
            int d = db + p * 4;
            Qs[nn][d] = qp[(size_t)d * NPIX];
        }
    }
    // stage K: KVs[l][d]
    {
        const float* kp = kvbuf + (size_t)(b * 1024 + h * HD) * LTOK + tid;
#pragma unroll
        for (int d = 0; d < HD; ++d)
            KVs[tid][d] = kp[(size_t)d * LTOK];
    }
    __syncthreads();

    // sim GEMM: thread (lg,ng): n = ng*4+i, l = lg + 16*j (interleaved to avoid bank conflicts)
    const int lg = tid >> 4, ng = tid & 15;
    float acc[4][16];
#pragma unroll
    for (int i = 0; i < 4; ++i)
#pragma unroll
        for (int j = 0; j < 16; ++j) acc[i][j] = 0.f;

#pragma unroll 2
    for (int kk = 0; kk < HD; kk += 4) {
        float qv[4][4];
#pragma unroll
        for (int i = 0; i < 4; ++i)
            *(float4*)qv[i] = *(const float4*)&Qs[ng * 4 + i][kk];
#pragma unroll
        for (int j = 0; j < 16; ++j) {
            float kv4[4];
            *(float4*)kv4 = *(const float4*)&KVs[lg + 16 * j][kk];
#pragma unroll
            for (int i = 0; i < 4; ++i)
                acc[i][j] += qv[i][0] * kv4[0] + qv[i][1] * kv4[1] +
                             qv[i][2] * kv4[2] + qv[i][3] * kv4[3];
        }
    }
    // epilogue: sim = (qk + log(m*md + eps)) * scale  -> Ss[l][n]
    {
        float mreg[4];
#pragma unroll
        for (int i = 0; i < 4; ++i)
            mreg[i] = mask[(size_t)bb * NPIX + n0 + ng * 4 + i];
#pragma unroll
        for (int j = 0; j < 16; ++j) {
            int l = lg + 16 * j;
            float mdv = md[bb * LTOK + l];
            float v[4];
#pragma unroll
            for (int i = 0; i < 4; ++i)
                v[i] = (acc[i][j] + logf(mreg[i] * mdv + EPSB)) * SCALEF;
            *(float4*)&Ss[l][ng * 4] = *(float4*)v;
        }
    }
    __syncthreads();

    // stage V (overwrite KVs) + softmax over l per n (4 lanes per row)
    {
        const float* vp = kvbuf + (size_t)(b * 1024 + 512 + h * HD) * LTOK + tid;
#pragma unroll
        for (int d = 0; d < HD; ++d)
            KVs[tid][d] = vp[(size_t)d * LTOK];
    }
    {
        const int n = tid >> 2, t = tid & 3;
        float s[64];
#pragma unroll
        for (int ii = 0; ii < 64; ++ii) s[ii] = Ss[t + 4 * ii][n];
        float mx = s[0];
#pragma unroll
        for (int ii = 1; ii < 64; ++ii) mx = fmaxf(mx, s[ii]);
        mx = fmaxf(mx, __shfl_xor(mx, 1));
        mx = fmaxf(mx, __shfl_xor(mx, 2));
        float sum = 0.f;
#pragma unroll
        for (int ii = 0; ii < 64; ++ii) {
            s[ii] = expf(s[ii] - mx);
            sum += s[ii];
        }
        sum += __shfl_xor(sum, 1);
        sum += __shfl_xor(sum, 2);
#pragma unroll
        for (int ii = 0; ii < 64; ++ii) Ss[t + 4 * ii][n] = s[ii];
        if (t == 0) invs[n] = 1.f / sum;
    }
    __syncthreads();

    // PV: out[n,d] = inv[n] * sum_l e[l,n] * V[l,d];  thread (dg,ng): d=dg*4+j, n=ng*4+i
    {
        const int dg = tid >> 4;
        float acc2[4][4] = {{0.f}};
#pragma unroll 8
        for (int kk = 0; kk < LTOK; ++kk) {
            float sv[4], vv[4];
            *(float4*)sv = *(const float4*)&Ss[kk][ng * 4];
            *(float4*)vv = *(const float4*)&KVs[kk][dg * 4];
#pragma unroll
            for (int i = 0; i < 4; ++i)
#pragma unroll
                for (int j = 0; j < 4; ++j)
                    acc2[i][j] += sv[i] * vv[j];
        }
        float iv[4];
#pragma unroll
        for (int i = 0; i < 4; ++i) iv[i] = invs[ng * 4 + i];
        float* op = obuf + (size_t)(b * DIMC + h * HD) * NPIX;
#pragma unroll
        for (int j = 0; j < 4; ++j) {
            int d = dg * 4 + j;
            float4 ov = make_float4(acc2[0][j] * iv[0], acc2[1][j] * iv[1],
                                    acc2[2][j] * iv[2], acc2[3][j] * iv[3]);
            *(float4*)&op[(size_t)d * NPIX + n0 + ng * 4] = ov;
        }
    }
}

extern "C" void kernel_launch(void* const* d_in, const int* in_sizes, int n_in,
                              void* d_out, int out_size, void* d_ws, size_t ws_size,
                              hipStream_t stream) {
    const float* x    = (const float*)d_in[0];
    const float* mask = (const float*)d_in[1];
    const float* Wq   = (const float*)d_in[2];
    const float* Wkv  = (const float*)d_in[3];
    const float* Wo   = (const float*)d_in[4];
    float* out = (float*)d_out;

    char* ws = (char*)d_ws;
    float* md   = (float*)(ws);                                    // 512 f
    float* q    = (float*)(ws + 4096);                             // 64MB
    float* ao   = (float*)(ws + 4096 + 67108864);                  // 64MB (attn out)
    float* part = (float*)(ws + 4096 + 67108864);                  // 32MB, ALIASES ao:
                                                                   // consumed by k_kvreduce before k_attn writes ao
    float* kv   = (float*)(ws + 4096 + 2 * 67108864);              // 2MB

    k_maskdown<<<dim3(BATCH), dim3(256), 0, stream>>>(mask, md);
    k_conv1x1<<<dim3(NPIX / 64, DIMC / 64, BATCH), dim3(256), 0, stream>>>(x, Wq, q);
    k_convkv<<<dim3(LTOK / 64, 1024 / 64, BATCH * SPLITK), dim3(256), 0, stream>>>(x, Wkv, part);
    k_kvreduce<<<dim3(2048), dim3(256), 0, stream>>>(part, kv);
    k_attn<<<dim3(NPIX / 64, BATCH * HEADS), dim3(256), 0, stream>>>(q, kv, mask, md, ao);
    k_conv1x1<<<dim3(NPIX / 64, DIMC / 64, BATCH), dim3(256), 0, stream>>>(ao, Wo, out);
}

// Round 3
// 715.922 us; speedup vs baseline: 3.5003x; 2.2828x over previous
//
#include <hip/hip_runtime.h>
#include <math.h>

#define DIMC  512
#define HEADS 8
#define HD    64
#define NPIX  16384   // 128*128
#define LTOK  256     // 16*16
#define BATCH 2
#define WIMG  128
#define KVK   32768   // 512*8*8
#define EPSB  1e-8f
#define SCALEF 0.125f // 64^-0.5
#define SPLITK 16
#define KCHUNK (KVK / SPLITK)   // 2048

typedef unsigned short ushort_t;
using bf16x8 = __attribute__((ext_vector_type(8))) __bf16;
using f32x4  = __attribute__((ext_vector_type(4))) float;

__device__ __forceinline__ ushort_t f2bf(float f) {
    union { float f; unsigned u; } v; v.f = f;
    unsigned r = v.u + 0x7FFFu + ((v.u >> 16) & 1u);
    return (ushort_t)(r >> 16);
}
__device__ __forceinline__ float bf2f(ushort_t h) {
    union { unsigned u; float f; } v; v.u = ((unsigned)h) << 16;
    return v.f;
}
// async global->LDS, 16B per lane; lds base must be wave-uniform
__device__ __forceinline__ void gl16(const void* g, void* l) {
    __builtin_amdgcn_global_load_lds(
        (const __attribute__((address_space(1))) unsigned int*)g,
        (__attribute__((address_space(3))) unsigned int*)l, 16, 0, 0);
}

// ---------------- mask downsample (avg pool 8x8) ----------------
__global__ void k_maskdown(const float* __restrict__ mask, float* __restrict__ md) {
    int b = blockIdx.x;
    int l = threadIdx.x;
    int hr = l >> 4, wr = l & 15;
    const float* mp = mask + (size_t)b * NPIX;
    float s = 0.f;
#pragma unroll
    for (int i = 0; i < 8; ++i)
#pragma unroll
        for (int j = 0; j < 8; ++j)
            s += mp[(hr * 8 + i) * WIMG + wr * 8 + j];
    md[b * LTOK + l] = s * (1.f / 64.f);
}

// ---------------- x [b][c][n] f32 -> xt [b][n][c] bf16 (LDS transpose) ------
__global__ __launch_bounds__(256) void k_xt(const float* __restrict__ x, ushort_t* __restrict__ xt) {
    __shared__ float t[64][65];
    int b = blockIdx.z, c0 = blockIdx.y * 64, n0 = blockIdx.x * 64;
    int tn = threadIdx.x & 63, tc = threadIdx.x >> 6;
    const float* xb = x + ((size_t)b * DIMC + c0) * NPIX + n0;
#pragma unroll
    for (int p = 0; p < 16; ++p)
        t[tc + p * 4][tn] = xb[(size_t)(tc + p * 4) * NPIX + tn];
    __syncthreads();
    ushort_t* xtb = xt + ((size_t)b * NPIX + n0) * DIMC + c0;
#pragma unroll
    for (int p = 0; p < 16; ++p) {
        int nl = tc + p * 4;
        xtb[(size_t)nl * DIMC + tn] = f2bf(t[tn][nl]);
    }
}

// ---------------- Wkv [o][c][ij] f32 -> Wkvp [o][ij*512+c] bf16 ----------------
__global__ __launch_bounds__(256) void k_wkvp(const float* __restrict__ Wkv, ushort_t* __restrict__ Wp) {
    __shared__ float t[64][65];
    int o = blockIdx.y, c0 = blockIdx.x * 64;
    int tij = threadIdx.x & 63, tc = threadIdx.x >> 6;
    const float* wb = Wkv + ((size_t)o * DIMC + c0) * 64;
#pragma unroll
    for (int p = 0; p < 16; ++p)
        t[tc + p * 4][tij] = wb[(size_t)(tc + p * 4) * 64 + tij];
    __syncthreads();
    ushort_t* wpb = Wp + (size_t)o * KVK + c0;
#pragma unroll
    for (int p = 0; p < 16; ++p) {
        int ij = tc + p * 4;
        wpb[(size_t)ij * DIMC + tij] = f2bf(t[tij][ij]);
    }
}

// ---------------- straight f32 -> bf16 convert ----------------
__global__ void k_cvt(const float* __restrict__ s, ushort_t* __restrict__ d) {
    int i = blockIdx.x * 256 + threadIdx.x;
    d[i] = f2bf(s[i]);
}

// ================= MFMA GEMM (1x1 convs), 128x128 tile, BK=64 =================
// A [M][512] bf16 row-major (frag rows), B [colmax][512] bf16 (frag cols), K=512.
// EPI 0: Y = q bf16 [b][n][512], D rows = d.   EPI 1: Y = out f32 [b][o][n], D rows = n.
template<int EPI>
__global__ __launch_bounds__(256) void k_gemm_qo(
    const ushort_t* __restrict__ A, long sA,
    const ushort_t* __restrict__ B, long sB,
    void* __restrict__ Yv) {
    __shared__ ushort_t Asm[128 * 64];   // [row][k] 16KB
    __shared__ ushort_t Bsm[128 * 64];
    const int tid = threadIdx.x;
    const int w = tid >> 6, lane = tid & 63;
    const int wm = w >> 1, wn = w & 1;
    const int lr = lane & 15, lg = lane >> 4;
    const int bz = blockIdx.z;
    const int m0 = blockIdx.y * 128, c0 = blockIdx.x * 128;
    const ushort_t* Ab = A + (size_t)bz * sA;
    const ushort_t* Bb = B + (size_t)bz * sB;

    f32x4 acc[4][4];
    const f32x4 zz = {0.f, 0.f, 0.f, 0.f};
#pragma unroll
    for (int i = 0; i < 4; ++i)
#pragma unroll
        for (int j = 0; j < 4; ++j) acc[i][j] = zz;

    for (int k0 = 0; k0 < DIMC; k0 += 64) {
        __syncthreads();
#pragma unroll
        for (int r = 0; r < 4; ++r) {
            int slot = r * 256 + tid;           // [0,1024): row = slot>>3, kb = slot&7
            int m = slot >> 3, kb = slot & 7;
            gl16(Ab + (size_t)(m0 + m) * DIMC + k0 + kb * 8,
                 &Asm[(size_t)(r * 256 + w * 64) * 8]);
        }
#pragma unroll
        for (int r = 0; r < 4; ++r) {
            int slot = r * 256 + tid;
            int m = slot >> 3, kb = slot & 7;
            gl16(Bb + (size_t)(c0 + m) * DIMC + k0 + kb * 8,
                 &Bsm[(size_t)(r * 256 + w * 64) * 8]);
        }
        __syncthreads();
#pragma unroll
        for (int kk = 0; kk < 2; ++kk) {
            bf16x8 af[4], bfr[4];
#pragma unroll
            for (int i = 0; i < 4; ++i)
                af[i] = *(const bf16x8*)&Asm[(size_t)(wm * 64 + i * 16 + lr) * 64 + kk * 32 + lg * 8];
#pragma unroll
            for (int j = 0; j < 4; ++j)
                bfr[j] = *(const bf16x8*)&Bsm[(size_t)(wn * 64 + j * 16 + lr) * 64 + kk * 32 + lg * 8];
#pragma unroll
            for (int i = 0; i < 4; ++i)
#pragma unroll
                for (int j = 0; j < 4; ++j)
                    acc[i][j] = __builtin_amdgcn_mfma_f32_16x16x32_bf16(af[i], bfr[j], acc[i][j], 0, 0, 0);
        }
    }
    if (EPI == 0) {
        ushort_t* q = (ushort_t*)Yv + (size_t)bz * ((size_t)NPIX * DIMC);
#pragma unroll
        for (int i = 0; i < 4; ++i) {
            int d0 = m0 + wm * 64 + i * 16 + lg * 4;
#pragma unroll
            for (int j = 0; j < 4; ++j) {
                int n = c0 + wn * 64 + j * 16 + lr;
                ushort4 v;
                v.x = f2bf(acc[i][j][0]); v.y = f2bf(acc[i][j][1]);
                v.z = f2bf(acc[i][j][2]); v.w = f2bf(acc[i][j][3]);
                *(ushort4*)&q[(size_t)n * DIMC + d0] = v;
            }
        }
    } else {
        float* O = (float*)Yv + (size_t)bz * ((size_t)DIMC * NPIX);
#pragma unroll
        for (int i = 0; i < 4; ++i) {
            int n0r = m0 + wm * 64 + i * 16 + lg * 4;
#pragma unroll
            for (int j = 0; j < 4; ++j) {
                int o = c0 + wn * 64 + j * 16 + lr;
                *(f32x4*)&O[(size_t)o * NPIX + n0r] = acc[i][j];
            }
        }
    }
}

// ================= MFMA kv conv (im2col GEMM), split-K=16 =================
// A = Wkvp [1024][32768], B = im2col from xt. Partials Pt[z][l][o] f32 (transposed).
__global__ __launch_bounds__(256) void k_convkv_mfma(
    const ushort_t* __restrict__ xt, const ushort_t* __restrict__ Wp,
    float* __restrict__ part) {
    __shared__ ushort_t Asm[128 * 64];
    __shared__ ushort_t Bsm[128 * 64];
    const int tid = threadIdx.x;
    const int w = tid >> 6, lane = tid & 63;
    const int wm = w >> 1, wn = w & 1;
    const int lr = lane & 15, lg = lane >> 4;
    const int z = blockIdx.z;
    const int b = z >> 4, ks = z & 15;
    const int m0 = blockIdx.y * 128, n0 = blockIdx.x * 128;
    const ushort_t* xtb = xt + (size_t)b * NPIX * DIMC;
    const int kbeg = ks * KCHUNK;

    f32x4 acc[4][4];
    const f32x4 zz = {0.f, 0.f, 0.f, 0.f};
#pragma unroll
    for (int i = 0; i < 4; ++i)
#pragma unroll
        for (int j = 0; j < 4; ++j) acc[i][j] = zz;

    for (int k0 = kbeg; k0 < kbeg + KCHUNK; k0 += 64) {
        __syncthreads();
#pragma unroll
        for (int r = 0; r < 4; ++r) {
            int slot = r * 256 + tid;
            int m = slot >> 3, kb = slot & 7;
            gl16(Wp + (size_t)(m0 + m) * KVK + k0 + kb * 8,
                 &Asm[(size_t)(r * 256 + w * 64) * 8]);
        }
#pragma unroll
        for (int r = 0; r < 4; ++r) {
            int slot = r * 256 + tid;
            int nn = slot >> 3, kb = slot & 7;
            int l = n0 + nn, hr = l >> 4, wr = l & 15;
            int kp = k0 + kb * 8;
            int ij = kp >> 9, ck = kp & 511;
            int ii = ij >> 3, jj = ij & 7;
            gl16(xtb + (size_t)((hr * 8 + ii) * WIMG + wr * 8 + jj) * DIMC + ck,
                 &Bsm[(size_t)(r * 256 + w * 64) * 8]);
        }
        __syncthreads();
#pragma unroll
        for (int kk = 0; kk < 2; ++kk) {
            bf16x8 af[4], bfr[4];
#pragma unroll
            for (int i = 0; i < 4; ++i)
                af[i] = *(const bf16x8*)&Asm[(size_t)(wm * 64 + i * 16 + lr) * 64 + kk * 32 + lg * 8];
#pragma unroll
            for (int j = 0; j < 4; ++j)
                bfr[j] = *(const bf16x8*)&Bsm[(size_t)(wn * 64 + j * 16 + lr) * 64 + kk * 32 + lg * 8];
#pragma unroll
            for (int i = 0; i < 4; ++i)
#pragma unroll
                for (int j = 0; j < 4; ++j)
                    acc[i][j] = __builtin_amdgcn_mfma_f32_16x16x32_bf16(af[i], bfr[j], acc[i][j], 0, 0, 0);
        }
    }
    float* P = part + (size_t)z * (LTOK * 1024);
#pragma unroll
    for (int i = 0; i < 4; ++i) {
        int o0 = m0 + wm * 64 + i * 16 + lg * 4;
#pragma unroll
        for (int j = 0; j < 4; ++j) {
            int l = n0 + wn * 64 + j * 16 + lr;
            *(f32x4*)&P[(size_t)l * 1024 + o0] = acc[i][j];
        }
    }
}

// reduce partials -> kv [b][o][l] f32
__global__ void k_kvreduce(const float* __restrict__ part, float* __restrict__ kv) {
    int idx = blockIdx.x * 256 + threadIdx.x;   // [0, 2*1024*256)
    int o = idx & 1023;
    int rest = idx >> 10;
    int l = rest & 255, b = rest >> 8;
    float s = 0.f;
#pragma unroll
    for (int ks = 0; ks < SPLITK; ++ks)
        s += part[(size_t)(b * SPLITK + ks) * (LTOK * 1024) + (size_t)l * 1024 + o];
    kv[((size_t)b * 1024 + o) * LTOK + l] = s;
}

// ---------------- fused attention (fp32 this round) ----------------
// reads q bf16 [b][n][512], kv f32 [b][1024][256]; writes ao bf16 [b][n][512]
// bias batch quirk: bias index = (b*HEADS+h) % B
__global__ __launch_bounds__(256) void k_attn(const ushort_t* __restrict__ qbuf,
                                              const float* __restrict__ kvbuf,
                                              const float* __restrict__ mask,
                                              const float* __restrict__ md,
                                              ushort_t* __restrict__ obuf) {
    __shared__ float KVs[256][68];
    __shared__ float Qs[64][68];
    __shared__ float Ss[256][68];
    __shared__ float invs[64];

    const int n0 = blockIdx.x * 64;
    const int bh = blockIdx.y;
    const int b = bh >> 3, h = bh & 7;
    const int bb = bh % BATCH;
    const int tid = threadIdx.x;

    // stage Q from bf16 [n][c]
    {
        const int nn = tid >> 2, dq = (tid & 3) * 16;
        const ushort_t* qp = qbuf + ((size_t)b * NPIX + n0 + nn) * DIMC + h * HD + dq;
#pragma unroll
        for (int p = 0; p < 16; ++p)
            Qs[nn][dq + p] = bf2f(qp[p]);
    }
    // stage K
    {
        const float* kp = kvbuf + ((size_t)b * 1024 + h * HD) * LTOK + tid;
#pragma unroll
        for (int d = 0; d < HD; ++d)
            KVs[tid][d] = kp[(size_t)d * LTOK];
    }
    __syncthreads();

    const int lg = tid >> 4, ng = tid & 15;
    float acc[4][16];
#pragma unroll
    for (int i = 0; i < 4; ++i)
#pragma unroll
        for (int j = 0; j < 16; ++j) acc[i][j] = 0.f;

#pragma unroll 2
    for (int kk = 0; kk < HD; kk += 4) {
        float qv[4][4];
#pragma unroll
        for (int i = 0; i < 4; ++i)
            *(float4*)qv[i] = *(const float4*)&Qs[ng * 4 + i][kk];
#pragma unroll
        for (int j = 0; j < 16; ++j) {
            float kv4[4];
            *(float4*)kv4 = *(const float4*)&KVs[lg + 16 * j][kk];
#pragma unroll
            for (int i = 0; i < 4; ++i)
                acc[i][j] += qv[i][0] * kv4[0] + qv[i][1] * kv4[1] +
                             qv[i][2] * kv4[2] + qv[i][3] * kv4[3];
        }
    }
    {
        float mreg[4];
#pragma unroll
        for (int i = 0; i < 4; ++i)
            mreg[i] = mask[(size_t)bb * NPIX + n0 + ng * 4 + i];
#pragma unroll
        for (int j = 0; j < 16; ++j) {
            int l = lg + 16 * j;
            float mdv = md[bb * LTOK + l];
            float v[4];
#pragma unroll
            for (int i = 0; i < 4; ++i)
                v[i] = (acc[i][j] + logf(mreg[i] * mdv + EPSB)) * SCALEF;
            *(float4*)&Ss[l][ng * 4] = *(float4*)v;
        }
    }
    __syncthreads();

    // stage V (overwrite KVs) + softmax
    {
        const float* vp = kvbuf + ((size_t)b * 1024 + 512 + h * HD) * LTOK + tid;
#pragma unroll
        for (int d = 0; d < HD; ++d)
            KVs[tid][d] = vp[(size_t)d * LTOK];
    }
    {
        const int n = tid >> 2, t = tid & 3;
        float s[64];
#pragma unroll
        for (int ii = 0; ii < 64; ++ii) s[ii] = Ss[t + 4 * ii][n];
        float mx = s[0];
#pragma unroll
        for (int ii = 1; ii < 64; ++ii) mx = fmaxf(mx, s[ii]);
        mx = fmaxf(mx, __shfl_xor(mx, 1));
        mx = fmaxf(mx, __shfl_xor(mx, 2));
        float sum = 0.f;
#pragma unroll
        for (int ii = 0; ii < 64; ++ii) {
            s[ii] = expf(s[ii] - mx);
            sum += s[ii];
        }
        sum += __shfl_xor(sum, 1);
        sum += __shfl_xor(sum, 2);
#pragma unroll
        for (int ii = 0; ii < 64; ++ii) Ss[t + 4 * ii][n] = s[ii];
        if (t == 0) invs[n] = 1.f / sum;
    }
    __syncthreads();

    // PV + bf16 [n][c] store
    {
        const int dg = tid >> 4;
        float acc2[4][4] = {{0.f}};
#pragma unroll 8
        for (int kk = 0; kk < LTOK; ++kk) {
            float sv[4], vv[4];
            *(float4*)sv = *(const float4*)&Ss[kk][ng * 4];
            *(float4*)vv = *(const float4*)&KVs[kk][dg * 4];
#pragma unroll
            for (int i = 0; i < 4; ++i)
#pragma unroll
                for (int j = 0; j < 4; ++j)
                    acc2[i][j] += sv[i] * vv[j];
        }
        float iv[4];
#pragma unroll
        for (int i = 0; i < 4; ++i) iv[i] = invs[ng * 4 + i];
        ushort_t* aop = obuf + ((size_t)b * NPIX + n0) * DIMC + h * HD;
#pragma unroll
        for (int i = 0; i < 4; ++i) {
            ushort4 v;
            v.x = f2bf(acc2[i][0] * iv[i]);
            v.y = f2bf(acc2[i][1] * iv[i]);
            v.z = f2bf(acc2[i][2] * iv[i]);
            v.w = f2bf(acc2[i][3] * iv[i]);
            *(ushort4*)&aop[(size_t)(ng * 4 + i) * DIMC + dg * 4] = v;
        }
    }
}

extern "C" void kernel_launch(void* const* d_in, const int* in_sizes, int n_in,
                              void* d_out, int out_size, void* d_ws, size_t ws_size,
                              hipStream_t stream) {
    const float* x    = (const float*)d_in[0];
    const float* mask = (const float*)d_in[1];
    const float* Wq   = (const float*)d_in[2];
    const float* Wkv  = (const float*)d_in[3];
    const float* Wo   = (const float*)d_in[4];
    float* out = (float*)d_out;

    char* ws = (char*)d_ws;
    float*    md   = (float*)(ws);                         // 4 KB
    ushort_t* xt   = (ushort_t*)(ws + 4096);               // 33.55 MB
    ushort_t* wkvp = (ushort_t*)(ws + 33558528);           // 67.1 MB
    ushort_t* qbf  = wkvp;                                 // alias: written after convkv
    float*    kvb  = (float*)(ws + 100667392);             // 2 MB
    ushort_t* wqb  = (ushort_t*)(ws + 102764544);          // 0.5 MB
    ushort_t* wob  = wqb + 262144;                         // 0.5 MB
    float*    part = (float*)(ws + 103813120);             // 33.55 MB
    ushort_t* aob  = (ushort_t*)part;                      // alias: written after kvreduce

    k_maskdown<<<dim3(BATCH), dim3(256), 0, stream>>>(mask, md);
    k_xt<<<dim3(NPIX / 64, DIMC / 64, BATCH), dim3(256), 0, stream>>>(x, xt);
    k_cvt<<<dim3(1024), dim3(256), 0, stream>>>(Wq, wqb);
    k_cvt<<<dim3(1024), dim3(256), 0, stream>>>(Wo, wob);
    k_wkvp<<<dim3(DIMC / 64, 1024), dim3(256), 0, stream>>>(Wkv, wkvp);

    k_convkv_mfma<<<dim3(LTOK / 128, 1024 / 128, BATCH * SPLITK), dim3(256), 0, stream>>>(xt, wkvp, part);
    k_kvreduce<<<dim3(2048), dim3(256), 0, stream>>>(part, kvb);

    // q projection: A=Wq (M=512 d), B=xt (cols n), D[d][n] -> q bf16 [n][d]
    k_gemm_qo<0><<<dim3(NPIX / 128, DIMC / 128, BATCH), dim3(256), 0, stream>>>(
        wqb, 0L, xt, (long)NPIX * DIMC, qbf);

    k_attn<<<dim3(NPIX / 64, BATCH * HEADS), dim3(256), 0, stream>>>(qbf, kvb, mask, md, aob);

    // output projection: A=ao (M=16384 n), B=Wo (cols o), D[n][o] -> out f32 [o][n]
    k_gemm_qo<1><<<dim3(DIMC / 128, NPIX / 128, BATCH), dim3(256), 0, stream>>>(
        aob, (long)NPIX * DIMC, wob, 0L, out);
}

// Round 4
// 268.426 us; speedup vs baseline: 9.3358x; 2.6671x over previous
//
#include <hip/hip_runtime.h>
#include <math.h>

#define DIMC  512
#define HEADS 8
#define HD    64
#define NPIX  16384   // 128*128
#define LTOK  256     // 16*16
#define BATCH 2
#define WIMG  128
#define KVK   32768   // 512*8*8
#define EPSB  1e-8f
#define SCALEF 0.125f // 64^-0.5
#define SPLITK 16
#define KCHUNK (KVK / SPLITK)   // 2048

typedef unsigned short ushort_t;
typedef unsigned int uint_t;
using bf16x8 = __attribute__((ext_vector_type(8))) __bf16;
using f32x4  = __attribute__((ext_vector_type(4))) float;

__device__ __forceinline__ ushort_t f2bf(float f) {
    union { float f; unsigned u; } v; v.f = f;
    unsigned r = v.u + 0x7FFFu + ((v.u >> 16) & 1u);
    return (ushort_t)(r >> 16);
}
__device__ __forceinline__ float bf2f(ushort_t h) {
    union { unsigned u; float f; } v; v.u = ((unsigned)h) << 16;
    return v.f;
}
__device__ __forceinline__ uint_t pk2bf(float a, float b) {
    return (uint_t)f2bf(a) | ((uint_t)f2bf(b) << 16);
}
// async global->LDS, 16B per lane; lds base must be wave-uniform
__device__ __forceinline__ void gl16(const void* g, void* l) {
    __builtin_amdgcn_global_load_lds(
        (const __attribute__((address_space(1))) unsigned int*)g,
        (__attribute__((address_space(3))) unsigned int*)l, 16, 0, 0);
}

// ---------------- mask downsample (avg pool 8x8) ----------------
__global__ void k_maskdown(const float* __restrict__ mask, float* __restrict__ md) {
    int b = blockIdx.x;
    int l = threadIdx.x;
    int hr = l >> 4, wr = l & 15;
    const float* mp = mask + (size_t)b * NPIX;
    float s = 0.f;
#pragma unroll
    for (int i = 0; i < 8; ++i)
#pragma unroll
        for (int j = 0; j < 8; ++j)
            s += mp[(hr * 8 + i) * WIMG + wr * 8 + j];
    md[b * LTOK + l] = s * (1.f / 64.f);
}

// ---------------- x [b][c][n] f32 -> xt [b][n][c] bf16 (LDS transpose) ------
__global__ __launch_bounds__(256) void k_xt(const float* __restrict__ x, ushort_t* __restrict__ xt) {
    __shared__ float t[64][65];
    int b = blockIdx.z, c0 = blockIdx.y * 64, n0 = blockIdx.x * 64;
    int tn = threadIdx.x & 63, tc = threadIdx.x >> 6;
    const float* xb = x + ((size_t)b * DIMC + c0) * NPIX + n0;
#pragma unroll
    for (int p = 0; p < 16; ++p)
        t[tc + p * 4][tn] = xb[(size_t)(tc + p * 4) * NPIX + tn];
    __syncthreads();
    ushort_t* xtb = xt + ((size_t)b * NPIX + n0) * DIMC + c0;
#pragma unroll
    for (int p = 0; p < 16; ++p) {
        int nl = tc + p * 4;
        xtb[(size_t)nl * DIMC + tn] = f2bf(t[tn][nl]);
    }
}

// ---------------- Wkv [o][c][ij] f32 -> Wkvp [o][ij*512+c] bf16 ----------------
__global__ __launch_bounds__(256) void k_wkvp(const float* __restrict__ Wkv, ushort_t* __restrict__ Wp) {
    __shared__ float t[64][65];
    int o = blockIdx.y, c0 = blockIdx.x * 64;
    int tij = threadIdx.x & 63, tc = threadIdx.x >> 6;
    const float* wb = Wkv + ((size_t)o * DIMC + c0) * 64;
#pragma unroll
    for (int p = 0; p < 16; ++p)
        t[tc + p * 4][tij] = wb[(size_t)(tc + p * 4) * 64 + tij];
    __syncthreads();
    ushort_t* wpb = Wp + (size_t)o * KVK + c0;
#pragma unroll
    for (int p = 0; p < 16; ++p) {
        int ij = tc + p * 4;
        wpb[(size_t)ij * DIMC + tij] = f2bf(t[tij][ij]);
    }
}

// ---------------- straight f32 -> bf16 convert ----------------
__global__ void k_cvt(const float* __restrict__ s, ushort_t* __restrict__ d) {
    int i = blockIdx.x * 256 + threadIdx.x;
    d[i] = f2bf(s[i]);
}

// ================= MFMA GEMM (1x1 convs), 128x128 tile, BK=64 =================
template<int EPI>
__global__ __launch_bounds__(256) void k_gemm_qo(
    const ushort_t* __restrict__ A, long sA,
    const ushort_t* __restrict__ B, long sB,
    void* __restrict__ Yv) {
    __shared__ ushort_t Asm[128 * 64];
    __shared__ ushort_t Bsm[128 * 64];
    const int tid = threadIdx.x;
    const int w = tid >> 6, lane = tid & 63;
    const int wm = w >> 1, wn = w & 1;
    const int lr = lane & 15, lg = lane >> 4;
    const int bz = blockIdx.z;
    const int m0 = blockIdx.y * 128, c0 = blockIdx.x * 128;
    const ushort_t* Ab = A + (size_t)bz * sA;
    const ushort_t* Bb = B + (size_t)bz * sB;

    f32x4 acc[4][4];
    const f32x4 zz = {0.f, 0.f, 0.f, 0.f};
#pragma unroll
    for (int i = 0; i < 4; ++i)
#pragma unroll
        for (int j = 0; j < 4; ++j) acc[i][j] = zz;

    for (int k0 = 0; k0 < DIMC; k0 += 64) {
        __syncthreads();
#pragma unroll
        for (int r = 0; r < 4; ++r) {
            int slot = r * 256 + tid;
            int m = slot >> 3, kb = slot & 7;
            gl16(Ab + (size_t)(m0 + m) * DIMC + k0 + kb * 8,
                 &Asm[(size_t)(r * 256 + w * 64) * 8]);
        }
#pragma unroll
        for (int r = 0; r < 4; ++r) {
            int slot = r * 256 + tid;
            int m = slot >> 3, kb = slot & 7;
            gl16(Bb + (size_t)(c0 + m) * DIMC + k0 + kb * 8,
                 &Bsm[(size_t)(r * 256 + w * 64) * 8]);
        }
        __syncthreads();
#pragma unroll
        for (int kk = 0; kk < 2; ++kk) {
            bf16x8 af[4], bfr[4];
#pragma unroll
            for (int i = 0; i < 4; ++i)
                af[i] = *(const bf16x8*)&Asm[(size_t)(wm * 64 + i * 16 + lr) * 64 + kk * 32 + lg * 8];
#pragma unroll
            for (int j = 0; j < 4; ++j)
                bfr[j] = *(const bf16x8*)&Bsm[(size_t)(wn * 64 + j * 16 + lr) * 64 + kk * 32 + lg * 8];
#pragma unroll
            for (int i = 0; i < 4; ++i)
#pragma unroll
                for (int j = 0; j < 4; ++j)
                    acc[i][j] = __builtin_amdgcn_mfma_f32_16x16x32_bf16(af[i], bfr[j], acc[i][j], 0, 0, 0);
        }
    }
    if (EPI == 0) {
        ushort_t* q = (ushort_t*)Yv + (size_t)bz * ((size_t)NPIX * DIMC);
#pragma unroll
        for (int i = 0; i < 4; ++i) {
            int d0 = m0 + wm * 64 + i * 16 + lg * 4;
#pragma unroll
            for (int j = 0; j < 4; ++j) {
                int n = c0 + wn * 64 + j * 16 + lr;
                ushort4 v;
                v.x = f2bf(acc[i][j][0]); v.y = f2bf(acc[i][j][1]);
                v.z = f2bf(acc[i][j][2]); v.w = f2bf(acc[i][j][3]);
                *(ushort4*)&q[(size_t)n * DIMC + d0] = v;
            }
        }
    } else {
        float* O = (float*)Yv + (size_t)bz * ((size_t)DIMC * NPIX);
#pragma unroll
        for (int i = 0; i < 4; ++i) {
            int n0r = m0 + wm * 64 + i * 16 + lg * 4;
#pragma unroll
            for (int j = 0; j < 4; ++j) {
                int o = c0 + wn * 64 + j * 16 + lr;
                *(f32x4*)&O[(size_t)o * NPIX + n0r] = acc[i][j];
            }
        }
    }
}

// ================= MFMA kv conv (im2col GEMM), split-K=16 =================
__global__ __launch_bounds__(256) void k_convkv_mfma(
    const ushort_t* __restrict__ xt, const ushort_t* __restrict__ Wp,
    float* __restrict__ part) {
    __shared__ ushort_t Asm[128 * 64];
    __shared__ ushort_t Bsm[128 * 64];
    const int tid = threadIdx.x;
    const int w = tid >> 6, lane = tid & 63;
    const int wm = w >> 1, wn = w & 1;
    const int lr = lane & 15, lg = lane >> 4;
    const int z = blockIdx.z;
    const int b = z >> 4, ks = z & 15;
    const int m0 = blockIdx.y * 128, n0 = blockIdx.x * 128;
    const ushort_t* xtb = xt + (size_t)b * NPIX * DIMC;
    const int kbeg = ks * KCHUNK;

    f32x4 acc[4][4];
    const f32x4 zz = {0.f, 0.f, 0.f, 0.f};
#pragma unroll
    for (int i = 0; i < 4; ++i)
#pragma unroll
        for (int j = 0; j < 4; ++j) acc[i][j] = zz;

    for (int k0 = kbeg; k0 < kbeg + KCHUNK; k0 += 64) {
        __syncthreads();
#pragma unroll
        for (int r = 0; r < 4; ++r) {
            int slot = r * 256 + tid;
            int m = slot >> 3, kb = slot & 7;
            gl16(Wp + (size_t)(m0 + m) * KVK + k0 + kb * 8,
                 &Asm[(size_t)(r * 256 + w * 64) * 8]);
        }
#pragma unroll
        for (int r = 0; r < 4; ++r) {
            int slot = r * 256 + tid;
            int nn = slot >> 3, kb = slot & 7;
            int l = n0 + nn, hr = l >> 4, wr = l & 15;
            int kp = k0 + kb * 8;
            int ij = kp >> 9, ck = kp & 511;
            int ii = ij >> 3, jj = ij & 7;
            gl16(xtb + (size_t)((hr * 8 + ii) * WIMG + wr * 8 + jj) * DIMC + ck,
                 &Bsm[(size_t)(r * 256 + w * 64) * 8]);
        }
        __syncthreads();
#pragma unroll
        for (int kk = 0; kk < 2; ++kk) {
            bf16x8 af[4], bfr[4];
#pragma unroll
            for (int i = 0; i < 4; ++i)
                af[i] = *(const bf16x8*)&Asm[(size_t)(wm * 64 + i * 16 + lr) * 64 + kk * 32 + lg * 8];
#pragma unroll
            for (int j = 0; j < 4; ++j)
                bfr[j] = *(const bf16x8*)&Bsm[(size_t)(wn * 64 + j * 16 + lr) * 64 + kk * 32 + lg * 8];
#pragma unroll
            for (int i = 0; i < 4; ++i)
#pragma unroll
                for (int j = 0; j < 4; ++j)
                    acc[i][j] = __builtin_amdgcn_mfma_f32_16x16x32_bf16(af[i], bfr[j], acc[i][j], 0, 0, 0);
        }
    }
    float* P = part + (size_t)z * (LTOK * 1024);
#pragma unroll
    for (int i = 0; i < 4; ++i) {
        int o0 = m0 + wm * 64 + i * 16 + lg * 4;
#pragma unroll
        for (int j = 0; j < 4; ++j) {
            int l = n0 + wn * 64 + j * 16 + lr;
            *(f32x4*)&P[(size_t)l * 1024 + o0] = acc[i][j];
        }
    }
}

// reduce partials -> kt bf16 [b][h][l][64], vt bf16 [b][h][d][256]
__global__ void k_kvreduce(const float* __restrict__ part,
                           ushort_t* __restrict__ kt, ushort_t* __restrict__ vt) {
    int idx = blockIdx.x * 256 + threadIdx.x;   // [0, 2*256*1024)
    int o = idx & 1023;
    int rest = idx >> 10;
    int l = rest & 255, b = rest >> 8;
    float s = 0.f;
#pragma unroll
    for (int ks = 0; ks < SPLITK; ++ks)
        s += part[(size_t)(b * SPLITK + ks) * (LTOK * 1024) + (size_t)l * 1024 + o];
    int h = (o >> 6) & 7, d = o & 63;
    if (o < 512)
        kt[(((size_t)b * 8 + h) * 256 + l) * 64 + d] = f2bf(s);
    else
        vt[(((size_t)b * 8 + h) * 64 + d) * 256 + l] = f2bf(s);
}

// ================= MFMA fused attention =================
// block: one (b,h) x 128 q-rows; 4 waves, wave w owns n in [n0+32w, n0+32w+32)
// swapped QK^T: sim^T[l][n] = mfma(K, Q)  -> softmax lane-local over l
// PV^T: out^T[d][n] = mfma(V^T, P^T), P^T B-frags built via 2-shfl redistribution
__global__ __launch_bounds__(256, 2) void k_attn_mfma(
    const ushort_t* __restrict__ qbf, const ushort_t* __restrict__ kt,
    const ushort_t* __restrict__ vt, const float* __restrict__ mask,
    const float* __restrict__ md, ushort_t* __restrict__ obuf) {
    __shared__ ushort_t Qs[128 * 64];   // 16KB, rows 128B, 8 slots of 16B, XOR-swizzled
    __shared__ ushort_t Ks[256 * 64];   // 32KB
    __shared__ ushort_t Vs[64 * 256];   // 32KB, rows 512B, 32 slots

    const int tid = threadIdx.x;
    const int w = tid >> 6, lane = tid & 63;
    const int g = lane >> 4, ln = lane & 15;
    const int bh = blockIdx.y, b = bh >> 3, h = bh & 7;
    const int bb = bh & 1;              // bias batch quirk: (b*8+h) % 2
    const int n0 = blockIdx.x * 128;

    // ---- stage Q [128][64] (reg-staged, swizzle slot s -> s^(row&7)) ----
    {
        const ushort_t* src = qbf + ((size_t)b * NPIX + n0) * DIMC + h * 64;
#pragma unroll
        for (int p = 0; p < 4; ++p) {
            int id = p * 256 + tid;          // 1024 slots
            int r = id >> 3, s = id & 7;
            uint4 v = *(const uint4*)(src + (size_t)r * DIMC + s * 8);
            *(uint4*)&Qs[(r * 8 + (s ^ (r & 7))) * 8] = v;
        }
    }
    // ---- stage K [256][64] ----
    {
        const ushort_t* src = kt + (size_t)bh * 256 * 64;
#pragma unroll
        for (int p = 0; p < 8; ++p) {
            int id = p * 256 + tid;          // 2048 slots
            int r = id >> 3, s = id & 7;
            uint4 v = *(const uint4*)(src + r * 64 + s * 8);
            *(uint4*)&Ks[(r * 8 + (s ^ (r & 7))) * 8] = v;
        }
    }
    // ---- stage V^T [64][256] ----
    {
        const ushort_t* src = vt + (size_t)bh * 64 * 256;
#pragma unroll
        for (int p = 0; p < 8; ++p) {
            int id = p * 256 + tid;          // 2048 slots
            int r = id >> 5, s = id & 31;
            uint4 v = *(const uint4*)(src + r * 256 + s * 8);
            *(uint4*)&Vs[(r * 32 + (s ^ (r & 7))) * 8] = v;
        }
    }
    __syncthreads();

    // ---- QK^T: acc[nf][f] = sim^T frag; lane holds n = n0+32w+16nf+ln, l = f*16+g*4+r
    f32x4 acc[2][16];
    const f32x4 zz = {0.f, 0.f, 0.f, 0.f};
#pragma unroll
    for (int nf = 0; nf < 2; ++nf)
#pragma unroll
        for (int f = 0; f < 16; ++f) acc[nf][f] = zz;

    bf16x8 qf[2][2];
#pragma unroll
    for (int nf = 0; nf < 2; ++nf)
#pragma unroll
        for (int kk = 0; kk < 2; ++kk) {
            int nl = 32 * w + nf * 16 + ln;
            qf[nf][kk] = *(const bf16x8*)&Qs[(nl * 8 + ((kk * 4 + g) ^ (nl & 7))) * 8];
        }
#pragma unroll
    for (int f = 0; f < 16; ++f) {
#pragma unroll
        for (int kk = 0; kk < 2; ++kk) {
            int l = f * 16 + ln;
            bf16x8 kf = *(const bf16x8*)&Ks[(l * 8 + ((kk * 4 + g) ^ (l & 7))) * 8];
            acc[0][f] = __builtin_amdgcn_mfma_f32_16x16x32_bf16(kf, qf[0][kk], acc[0][f], 0, 0, 0);
            acc[1][f] = __builtin_amdgcn_mfma_f32_16x16x32_bf16(kf, qf[1][kk], acc[1][f], 0, 0, 0);
        }
    }

    // ---- bias + softmax (lane-local over l, then shfl_xor 16/32) ----
    float inv[2];
    uint2 pb[2][16];     // P^T bf16x4 per frag
#pragma unroll
    for (int nf = 0; nf < 2; ++nf) {
        float mval = mask[(size_t)bb * NPIX + n0 + 32 * w + nf * 16 + ln];
        float mx = -1e30f;
#pragma unroll
        for (int f = 0; f < 16; ++f) {
            float4 md4 = *(const float4*)&md[bb * LTOK + f * 16 + g * 4];
            float s0 = (acc[nf][f][0] + __logf(mval * md4.x + EPSB)) * SCALEF;
            float s1 = (acc[nf][f][1] + __logf(mval * md4.y + EPSB)) * SCALEF;
            float s2 = (acc[nf][f][2] + __logf(mval * md4.z + EPSB)) * SCALEF;
            float s3 = (acc[nf][f][3] + __logf(mval * md4.w + EPSB)) * SCALEF;
            acc[nf][f][0] = s0; acc[nf][f][1] = s1;
            acc[nf][f][2] = s2; acc[nf][f][3] = s3;
            mx = fmaxf(mx, fmaxf(fmaxf(s0, s1), fmaxf(s2, s3)));
        }
        mx = fmaxf(mx, __shfl_xor(mx, 16));
        mx = fmaxf(mx, __shfl_xor(mx, 32));
        float sum = 0.f;
#pragma unroll
        for (int f = 0; f < 16; ++f) {
            float p0 = __expf(acc[nf][f][0] - mx);
            float p1 = __expf(acc[nf][f][1] - mx);
            float p2 = __expf(acc[nf][f][2] - mx);
            float p3 = __expf(acc[nf][f][3] - mx);
            sum += (p0 + p1) + (p2 + p3);
            pb[nf][f].x = pk2bf(p0, p1);
            pb[nf][f].y = pk2bf(p2, p3);
        }
        sum += __shfl_xor(sum, 16);
        sum += __shfl_xor(sum, 32);
        inv[nf] = 1.f / sum;
    }

    // ---- PV^T: acc2[nf][df] = mfma(V^T frag, P^T B-frag) ----
    f32x4 acc2[2][4];
#pragma unroll
    for (int nf = 0; nf < 2; ++nf)
#pragma unroll
        for (int df = 0; df < 4; ++df) acc2[nf][df] = zz;

    const int srcLo = ((g & 1) << 5) + ln;   // lane 32*(g&1) + ln
    const bool selHi = (g >> 1);             // g in {2,3}: use frag 2ks+1
#pragma unroll
    for (int ks = 0; ks < 8; ++ks) {
        bf16x8 vf[4];
#pragma unroll
        for (int df = 0; df < 4; ++df) {
            int d = df * 16 + ln;
            vf[df] = *(const bf16x8*)&Vs[(d * 32 + ((ks * 4 + g) ^ (d & 7))) * 8];
        }
#pragma unroll
        for (int nf = 0; nf < 2; ++nf) {
            uint_t e0 = pb[nf][2 * ks].x,     e1 = pb[nf][2 * ks].y;
            uint_t o0 = pb[nf][2 * ks + 1].x, o1 = pb[nf][2 * ks + 1].y;
            uint_t lo0 = __shfl((int)e0, srcLo), lo1 = __shfl((int)e1, srcLo);
            uint_t lo0b = __shfl((int)o0, srcLo), lo1b = __shfl((int)o1, srcLo);
            uint_t hi0 = __shfl((int)e0, srcLo + 16), hi1 = __shfl((int)e1, srcLo + 16);
            uint_t hi0b = __shfl((int)o0, srcLo + 16), hi1b = __shfl((int)o1, srcLo + 16);
            union { uint_t u[4]; bf16x8 v; } bfr;
            bfr.u[0] = selHi ? lo0b : lo0;
            bfr.u[1] = selHi ? lo1b : lo1;
            bfr.u[2] = selHi ? hi0b : hi0;
            bfr.u[3] = selHi ? hi1b : hi1;
#pragma unroll
            for (int df = 0; df < 4; ++df)
                acc2[nf][df] = __builtin_amdgcn_mfma_f32_16x16x32_bf16(vf[df], bfr.v, acc2[nf][df], 0, 0, 0);
        }
    }

    // ---- epilogue: out^T[d][n] * inv[n] -> ao bf16 [b][n][512] ----
#pragma unroll
    for (int nf = 0; nf < 2; ++nf) {
        int n = n0 + 32 * w + nf * 16 + ln;
        ushort_t* op = obuf + ((size_t)b * NPIX + n) * DIMC + h * 64;
#pragma unroll
        for (int df = 0; df < 4; ++df) {
            ushort4 v;
            v.x = f2bf(acc2[nf][df][0] * inv[nf]);
            v.y = f2bf(acc2[nf][df][1] * inv[nf]);
            v.z = f2bf(acc2[nf][df][2] * inv[nf]);
            v.w = f2bf(acc2[nf][df][3] * inv[nf]);
            *(ushort4*)&op[df * 16 + g * 4] = v;
        }
    }
}

extern "C" void kernel_launch(void* const* d_in, const int* in_sizes, int n_in,
                              void* d_out, int out_size, void* d_ws, size_t ws_size,
                              hipStream_t stream) {
    const float* x    = (const float*)d_in[0];
    const float* mask = (const float*)d_in[1];
    const float* Wq   = (const float*)d_in[2];
    const float* Wkv  = (const float*)d_in[3];
    const float* Wo   = (const float*)d_in[4];
    float* out = (float*)d_out;

    char* ws = (char*)d_ws;
    float*    md   = (float*)(ws);                         // 4 KB
    ushort_t* xt   = (ushort_t*)(ws + 4096);               // 33.55 MB
    ushort_t* wkvp = (ushort_t*)(ws + 33558528);           // 67.1 MB
    ushort_t* qbf  = wkvp;                                 // alias: written after convkv
    ushort_t* ktb  = (ushort_t*)(ws + 100667392);          // 0.5 MB
    ushort_t* vtb  = ktb + 524288;                         // 0.5 MB
    ushort_t* wqb  = (ushort_t*)(ws + 102764544);          // 0.5 MB
    ushort_t* wob  = wqb + 262144;                         // 0.5 MB
    float*    part = (float*)(ws + 103813120);             // 33.55 MB
    ushort_t* aob  = (ushort_t*)part;                      // alias: written after kvreduce

    k_maskdown<<<dim3(BATCH), dim3(256), 0, stream>>>(mask, md);
    k_xt<<<dim3(NPIX / 64, DIMC / 64, BATCH), dim3(256), 0, stream>>>(x, xt);
    k_cvt<<<dim3(1024), dim3(256), 0, stream>>>(Wq, wqb);
    k_cvt<<<dim3(1024), dim3(256), 0, stream>>>(Wo, wob);
    k_wkvp<<<dim3(DIMC / 64, 1024), dim3(256), 0, stream>>>(Wkv, wkvp);

    k_convkv_mfma<<<dim3(LTOK / 128, 1024 / 128, BATCH * SPLITK), dim3(256), 0, stream>>>(xt, wkvp, part);
    k_kvreduce<<<dim3(2048), dim3(256), 0, stream>>>(part, ktb, vtb);

    k_gemm_qo<0><<<dim3(NPIX / 128, DIMC / 128, BATCH), dim3(256), 0, stream>>>(
        wqb, 0L, xt, (long)NPIX * DIMC, qbf);

    k_attn_mfma<<<dim3(NPIX / 128, BATCH * HEADS), dim3(256), 0, stream>>>(
        qbf, ktb, vtb, mask, md, aob);

    k_gemm_qo<1><<<dim3(DIMC / 128, NPIX / 128, BATCH), dim3(256), 0, stream>>>(
        aob, (long)NPIX * DIMC, wob, 0L, out);
}